// Round 3
// baseline (776.174 us; speedup 1.0000x reference)
//
#include <hip/hip_runtime.h>
#include <hip/hip_bf16.h>
#include <math.h>

#define B_ 64
#define H_ 1024
#define E_ 1024
#define S_ 1024
#define V_ 50257

typedef __attribute__((ext_vector_type(4))) float f32x4;
typedef __attribute__((ext_vector_type(8))) short bf16x8;
typedef unsigned short ushort_t;
typedef unsigned int uint_t;

__device__ __forceinline__ float dot4(f32x4 a, f32x4 b) {
    return a[0]*b[0] + a[1]*b[1] + a[2]*b[2] + a[3]*b[3];
}
__device__ __forceinline__ float wave_sum(float v) {
    #pragma unroll
    for (int off = 32; off; off >>= 1) v += __shfl_xor(v, off);
    return v;
}
__device__ __forceinline__ ushort_t f2bf(float f) {
    uint_t u = __float_as_uint(f);
    uint_t r = (u + 0x7fffu + ((u >> 16) & 1u)) >> 16;
    return (ushort_t)r;
}

// ---------------------------------------------------------------- K1: GRU ---
// grid 512 x 256.  Block: 2 output j's, all 64 b's.  Wave: 16 b's.
// Weights staged once per block -> w_ih+w_hh HBM traffic = 25 MB (read once).
__global__ __launch_bounds__(256) void gru_kernel(
    const int* __restrict__ seq, const float* __restrict__ h0,
    const float* __restrict__ emb,
    const float* __restrict__ w_ih, const float* __restrict__ w_hh,
    const float* __restrict__ b_ih, const float* __restrict__ b_hh,
    float* __restrict__ hnew, float* __restrict__ hid)
{
    __shared__ float wsm[12 * 1024];          // 48 KB: 2 j's x 6 gate-rows
    const int jbase = blockIdx.x * 2;
    for (int idx = threadIdx.x; idx < 12 * 1024; idx += 256) {
        int row = idx >> 10, k = idx & 1023;
        int jj = (row >= 6) ? 1 : 0, g = row - jj * 6;
        int j = jbase + jj;
        wsm[idx] = (g < 3) ? w_ih[(size_t)(g * H_ + j) * E_ + k]
                           : w_hh[(size_t)((g - 3) * H_ + j) * H_ + k];
    }
    __syncthreads();
    const int wave = threadIdx.x >> 6, lane = threadIdx.x & 63;
    const f32x4* wsm4 = (const f32x4*)wsm;
    for (int ib = 0; ib < 16; ++ib) {
        const int b = wave * 16 + ib;
        const float* xp = emb + (size_t)seq[b] * E_;
        const float* hp = h0 + b * H_;
        f32x4 xv[4], hv[4];
        #pragma unroll
        for (int g = 0; g < 4; ++g) {
            xv[g] = *(const f32x4*)(xp + lane * 4 + 256 * g);
            hv[g] = *(const f32x4*)(hp + lane * 4 + 256 * g);
        }
        #pragma unroll
        for (int jj = 0; jj < 2; ++jj) {
            const int j = jbase + jj;
            float s0 = 0.f, s1 = 0.f, s2 = 0.f, s3 = 0.f, s4 = 0.f, s5 = 0.f;
            #pragma unroll
            for (int g = 0; g < 4; ++g) {
                int kk = lane + 64 * g;
                s0 += dot4(xv[g], wsm4[(jj * 6 + 0) * 256 + kk]);
                s1 += dot4(xv[g], wsm4[(jj * 6 + 1) * 256 + kk]);
                s2 += dot4(xv[g], wsm4[(jj * 6 + 2) * 256 + kk]);
                s3 += dot4(hv[g], wsm4[(jj * 6 + 3) * 256 + kk]);
                s4 += dot4(hv[g], wsm4[(jj * 6 + 4) * 256 + kk]);
                s5 += dot4(hv[g], wsm4[(jj * 6 + 5) * 256 + kk]);
            }
            s0 = wave_sum(s0); s1 = wave_sum(s1); s2 = wave_sum(s2);
            s3 = wave_sum(s3); s4 = wave_sum(s4); s5 = wave_sum(s5);
            if (lane == 0) {
                float gir = s0 + b_ih[j];
                float giz = s1 + b_ih[H_ + j];
                float gin = s2 + b_ih[2 * H_ + j];
                float ghr = s3 + b_hh[j];
                float ghz = s4 + b_hh[H_ + j];
                float ghn = s5 + b_hh[2 * H_ + j];
                float r = 1.f / (1.f + __expf(-(gir + ghr)));
                float z = 1.f / (1.f + __expf(-(giz + ghz)));
                float n = tanhf(gin + r * ghn);
                float hvj = hp[j];
                float hn2 = (1.f - z) * n + z * hvj;
                hnew[b * H_ + j] = hn2;
                hid[b * H_ + j]  = hn2;
            }
        }
    }
}

// -------------------------------------------- K2: attention partials (fused) ---
// grid (64,16) x 256.  Wave = 16 s-values with online softmax; enc read ONCE.
// 4096 waves (16/CU) to saturate the 268 MB stream.
__global__ __launch_bounds__(256) void attn_part_kernel(
    const float* __restrict__ hnew, const float* __restrict__ enc,
    float* __restrict__ pacc, float* __restrict__ pml)
{
    const int b = blockIdx.x, sb = blockIdx.y;
    const int wave = threadIdx.x >> 6, lane = threadIdx.x & 63;
    const int wg = sb * 4 + wave;          // 0..63 partial index
    const f32x4* hp = (const f32x4*)(hnew + b * H_);
    f32x4 hv[4];
    #pragma unroll
    for (int g = 0; g < 4; ++g) hv[g] = hp[lane + 64 * g];
    float m = -1e30f, l = 0.f;
    f32x4 a[4];
    #pragma unroll
    for (int g = 0; g < 4; ++g) a[g] = (f32x4){0.f, 0.f, 0.f, 0.f};
    const int s0 = wg * 16;
    for (int it = 0; it < 16; ++it) {
        const f32x4* ep = (const f32x4*)(enc + (((size_t)b * S_ + s0 + it) << 10));
        f32x4 e[4];
        #pragma unroll
        for (int g = 0; g < 4; ++g) e[g] = ep[lane + 64 * g];
        float p = 0.f;
        #pragma unroll
        for (int g = 0; g < 4; ++g) p += dot4(hv[g], e[g]);
        p = wave_sum(p);                   // identical value on all 64 lanes
        if (p <= m) {
            float w = __expf(p - m);
            l += w;
            #pragma unroll
            for (int g = 0; g < 4; ++g) a[g] += w * e[g];
        } else {                           // wave-uniform branch (no divergence)
            float sc = __expf(m - p);
            l = l * sc + 1.f;
            #pragma unroll
            for (int g = 0; g < 4; ++g) a[g] = a[g] * sc + e[g];
            m = p;
        }
    }
    f32x4* pa4 = (f32x4*)(pacc + ((size_t)(b * 64 + wg) << 10));
    #pragma unroll
    for (int g = 0; g < 4; ++g) pa4[lane + 64 * g] = a[g];
    if (lane == 0) {
        pml[(b * 64 + wg) * 2 + 0] = m;
        pml[(b * 64 + wg) * 2 + 1] = l;
    }
}

// ---------------------------------------------------- K3: merge partials ---
__global__ __launch_bounds__(256) void attn_merge_kernel(
    const float* __restrict__ pacc, const float* __restrict__ pml,
    float* __restrict__ ctx)
{
    const int b = blockIdx.x;
    float M = -1e30f;
    #pragma unroll
    for (int i = 0; i < 64; ++i) M = fmaxf(M, pml[(b * 64 + i) * 2]);
    float L = 0.f;
    #pragma unroll
    for (int i = 0; i < 64; ++i)
        L += __expf(pml[(b * 64 + i) * 2] - M) * pml[(b * 64 + i) * 2 + 1];
    const int h = threadIdx.x * 4;
    f32x4 c = (f32x4){0.f, 0.f, 0.f, 0.f};
    #pragma unroll
    for (int i = 0; i < 64; ++i) {
        float w = __expf(pml[(b * 64 + i) * 2] - M);
        c += w * *(const f32x4*)(pacc + ((size_t)(b * 64 + i) << 10) + h);
    }
    float inv = 1.f / L;
    *(f32x4*)(ctx + b * H_ + h) = c * inv;
}

// ------------------------------------------- K4: concat GEMM + tanh -> bf16 ---
// grid 512 x 256.  Block: 2 output j's, all 64 b's.  cw read once (8 MB).
__global__ __launch_bounds__(256) void concat_kernel(
    const float* __restrict__ hnew, const float* __restrict__ ctx,
    const float* __restrict__ cw, const float* __restrict__ cb,
    ushort_t* __restrict__ cbf)
{
    __shared__ float wsm[2 * 2048];           // 16 KB
    const int jbase = blockIdx.x * 2;
    for (int idx = threadIdx.x; idx < 2 * 2048; idx += 256) {
        int row = idx >> 11, k = idx & 2047;
        wsm[idx] = cw[(size_t)(jbase + row) * 2048 + k];
    }
    __syncthreads();
    const int wave = threadIdx.x >> 6, lane = threadIdx.x & 63;
    const f32x4* w4 = (const f32x4*)wsm;
    for (int ib = 0; ib < 16; ++ib) {
        const int b = wave * 16 + ib;
        f32x4 hv[4], cv[4];
        #pragma unroll
        for (int g = 0; g < 4; ++g) {
            hv[g] = *(const f32x4*)(hnew + b * H_ + lane * 4 + 256 * g);
            cv[g] = *(const f32x4*)(ctx  + b * H_ + lane * 4 + 256 * g);
        }
        #pragma unroll
        for (int jj = 0; jj < 2; ++jj) {
            float s = 0.f;
            #pragma unroll
            for (int g = 0; g < 4; ++g) {
                int kk = lane + 64 * g;
                s += dot4(hv[g], w4[jj * 512 + kk]);
                s += dot4(cv[g], w4[jj * 512 + 256 + kk]);
            }
            s = wave_sum(s);
            if (lane == 0) {
                int j = jbase + jj;
                cbf[b * H_ + j] = f2bf(tanhf(s + cb[j]));
            }
        }
    }
}

// ----------------------------- K5: [64,50257] x K=1024 bf16 MFMA GEMM ------
// grid 786 x 256 (4 waves).  Wave: 16 v-cols, all 64 b-rows.
// HBM floor: out_w = 206 MB read once.
__global__ __launch_bounds__(256) void biggemm_kernel(
    const ushort_t* __restrict__ cbf, const float* __restrict__ out_w,
    const float* __restrict__ out_b, float* __restrict__ logits)
{
    __shared__ ushort_t As[64 * 512];         // 64 KB, XOR-swizzled (G4)
    const int wave = threadIdx.x >> 6, lane = threadIdx.x & 63;
    const int col = lane & 15, kgrp = lane >> 4;
    const int vbase = blockIdx.x * 64 + wave * 16;
    int vr = vbase + col; if (vr > V_ - 1) vr = V_ - 1;
    const float* wp = out_w + (size_t)vr * 1024;
    f32x4 acc[4];
    #pragma unroll
    for (int mf = 0; mf < 4; ++mf) acc[mf] = (f32x4){0.f, 0.f, 0.f, 0.f};

    const uint_t* src = (const uint_t*)cbf;
    for (int kh = 0; kh < 2; ++kh) {
        if (kh) __syncthreads();
        // stage A half-tile (64 rows x 512 bf16) with row-XOR swizzle
        for (int r = 0; r < 64; ++r) {
            uint_t val = src[r * 512 + kh * 256 + threadIdx.x];
            int byte = (r << 10) | (threadIdx.x << 2);
            byte ^= (r & 7) << 4;
            *(uint_t*)((char*)As + byte) = val;
        }
        __syncthreads();
        #pragma unroll 4
        for (int ks = 0; ks < 16; ++ks) {
            // B fragment: 8 f32 from this v-row, cvt to bf16
            // B[k][j]: lane holds k = kgrp*8+i (i=0..7), j = col
            const float* bpf = wp + kh * 512 + ks * 32 + kgrp * 8;
            f32x4 b0 = *(const f32x4*)bpf;
            f32x4 b1 = *(const f32x4*)(bpf + 4);
            bf16x8 bfr;
            #pragma unroll
            for (int c = 0; c < 4; ++c) bfr[c]     = (short)f2bf(b0[c]);
            #pragma unroll
            for (int c = 0; c < 4; ++c) bfr[4 + c] = (short)f2bf(b1[c]);
            // A fragments from LDS (swizzled): lane holds A[col][kgrp*8+i]
            bf16x8 afr[4];
            #pragma unroll
            for (int mf = 0; mf < 4; ++mf) {
                int row = mf * 16 + col;
                int byte = row * 1024 + ks * 64 + kgrp * 16;
                byte ^= (row & 7) << 4;
                afr[mf] = *(const bf16x8*)((const char*)As + byte);
            }
            #pragma unroll
            for (int mf = 0; mf < 4; ++mf)
                acc[mf] = __builtin_amdgcn_mfma_f32_16x16x32_bf16(afr[mf], bfr, acc[mf], 0, 0, 0);
        }
    }
    const int v = vbase + col;
    if (v < V_) {
        float bias = out_b[v];
        #pragma unroll
        for (int mf = 0; mf < 4; ++mf) {
            #pragma unroll
            for (int r = 0; r < 4; ++r) {
                int brow = mf * 16 + kgrp * 4 + r;   // C/D: col=lane&15, row=(lane>>4)*4+reg
                logits[(size_t)brow * V_ + v] = acc[mf][r] + bias;
            }
        }
    }
}

// -------------------------------------------- K6: in-place log-softmax ------
__global__ __launch_bounds__(1024) void logsoftmax_kernel(float* __restrict__ logits)
{
    const int b = blockIdx.x;
    float* row = logits + (size_t)b * V_;
    __shared__ float redm[16], reds[16];
    const int lane = threadIdx.x & 63, wid = threadIdx.x >> 6;
    float m = -1e30f;
    for (int v = threadIdx.x; v < V_; v += 1024) m = fmaxf(m, row[v]);
    #pragma unroll
    for (int off = 32; off; off >>= 1) m = fmaxf(m, __shfl_xor(m, off));
    if (lane == 0) redm[wid] = m;
    __syncthreads();
    float M = redm[0];
    #pragma unroll
    for (int i = 1; i < 16; ++i) M = fmaxf(M, redm[i]);
    float s = 0.f;
    for (int v = threadIdx.x; v < V_; v += 1024) s += __expf(row[v] - M);
    #pragma unroll
    for (int off = 32; off; off >>= 1) s += __shfl_xor(s, off);
    if (lane == 0) reds[wid] = s;
    __syncthreads();
    float S = 0.f;
    #pragma unroll
    for (int i = 0; i < 16; ++i) S += reds[i];
    const float corr = M + logf(S);
    for (int v = threadIdx.x; v < V_; v += 1024) row[v] -= corr;
}

// ---------------------------------------------------------------------------
extern "C" void kernel_launch(void* const* d_in, const int* in_sizes, int n_in,
                              void* d_out, int out_size, void* d_ws, size_t ws_size,
                              hipStream_t stream)
{
    const int*   seq  = (const int*)d_in[0];
    const float* h0   = (const float*)d_in[1];
    const float* enc  = (const float*)d_in[2];
    const float* emb  = (const float*)d_in[3];
    const float* w_ih = (const float*)d_in[4];
    const float* w_hh = (const float*)d_in[5];
    const float* b_ih = (const float*)d_in[6];
    const float* b_hh = (const float*)d_in[7];
    const float* cw   = (const float*)d_in[8];
    const float* cb   = (const float*)d_in[9];
    const float* ow   = (const float*)d_in[10];
    const float* ob   = (const float*)d_in[11];

    float* out        = (float*)d_out;                 // [64, 50257] logits -> log-softmax in place
    float* hidden_out = out + (size_t)B_ * V_;         // [1, 64, 1024]

    char* wsb   = (char*)d_ws;
    float* hnew = (float*)wsb;                         // 256 KB
    float* ctx  = (float*)(wsb + (256 << 10));         // 256 KB
    ushort_t* cbf = (ushort_t*)(wsb + (512 << 10));    // 128 KB
    float* pml  = (float*)(wsb + (640 << 10));         // 32 KB
    float* pacc = (float*)(wsb + (1 << 20));           // 16 MB

    gru_kernel<<<512, 256, 0, stream>>>(seq, h0, emb, w_ih, w_hh, b_ih, b_hh, hnew, hidden_out);
    attn_part_kernel<<<dim3(64, 16), 256, 0, stream>>>(hnew, enc, pacc, pml);
    attn_merge_kernel<<<64, 256, 0, stream>>>(pacc, pml, ctx);
    concat_kernel<<<512, 256, 0, stream>>>(hnew, ctx, cw, cb, cbf);
    biggemm_kernel<<<786, 256, 0, stream>>>(cbf, ow, ob, out);
    logsoftmax_kernel<<<64, 1024, 0, stream>>>(out);
}